// Round 10
// baseline (203.574 us; speedup 1.0000x reference)
//
#include <hip/hip_runtime.h>
#include <hip/hip_bf16.h>

typedef short bf16x8 __attribute__((ext_vector_type(8)));
typedef float f32x4 __attribute__((ext_vector_type(4)));
typedef unsigned short u16;

#define B_   16
#define S_   1024
#define F_   512
#define H_   8
#define DK_  64

// Inputs/outputs are FLOAT32 (established rounds 3/7). cvt_all converts x +
// weights to bf16 once; all hot loops are pure bf16. Intermediates bf16.

__device__ __forceinline__ u16 f2bf(float f) {
    union { float f; unsigned int u; } v; v.f = f;
    return (u16)((v.u + 0x7FFFu + ((v.u >> 16) & 1u)) >> 16);
}
__device__ __forceinline__ float bf2f(u16 h) {
    union { unsigned int u; float f; } v; v.u = ((unsigned int)h) << 16;
    return v.f;
}
__device__ __forceinline__ bf16x8 cvt8(float4 a, float4 b) {
    union { u16 u[8]; bf16x8 v; } r;
    r.u[0] = f2bf(a.x); r.u[1] = f2bf(a.y); r.u[2] = f2bf(a.z); r.u[3] = f2bf(a.w);
    r.u[4] = f2bf(b.x); r.u[5] = f2bf(b.y); r.u[6] = f2bf(b.z); r.u[7] = f2bf(b.w);
    return r.v;
}
// pair-pack f32->bf16 (compiler emits v_cvt_pk_bf16_f32; RNE, matches f2bf)
__device__ __forceinline__ unsigned int pk2(float lo, float hi) {
    union { __hip_bfloat162 h; unsigned int u; } c;
    c.h = __float22bfloat162_rn(make_float2(lo, hi));
    return c.u;
}

// async global->LDS, 16 B per lane. LDS dest = wave-uniform base + lane*16.
__device__ __forceinline__ void gl_lds16(const u16* g, u16* l) {
    __builtin_amdgcn_global_load_lds(
        (const __attribute__((address_space(1))) unsigned int*)g,
        (__attribute__((address_space(3))) unsigned int*)l,
        16, 0, 0);
}

// ---------------------------------------------------------------------------
// One-shot f32 -> bf16 conversion of x and all weights/biases.
// unit = 8 elems. Segments (units): x 1048576 | WQ/WK/WV/WO 32768 each |
// bq/bk/bv/bo 64 each. grid 4609 x 256 (exact).
// ---------------------------------------------------------------------------
__global__ __launch_bounds__(256) void cvt_all(
    const float* __restrict__ x,
    const float* __restrict__ wq, const float* __restrict__ wk,
    const float* __restrict__ wv, const float* __restrict__ wo,
    const float* __restrict__ bq, const float* __restrict__ bk,
    const float* __restrict__ bv, const float* __restrict__ bo,
    u16* __restrict__ Xbf, u16* __restrict__ Wbase)
{
    const size_t u = (size_t)blockIdx.x * 256 + threadIdx.x;
    const float* src; u16* dst;
    if (u < 1048576)      { src = x  + u * 8;               dst = Xbf + u * 8; }
    else if (u < 1081344) { src = wq + (u - 1048576) * 8;   dst = Wbase + (u - 1048576) * 8; }
    else if (u < 1114112) { src = wk + (u - 1081344) * 8;   dst = Wbase +  262144 + (u - 1081344) * 8; }
    else if (u < 1146880) { src = wv + (u - 1114112) * 8;   dst = Wbase +  524288 + (u - 1114112) * 8; }
    else if (u < 1179648) { src = wo + (u - 1146880) * 8;   dst = Wbase +  786432 + (u - 1146880) * 8; }
    else if (u < 1179712) { src = bq + (u - 1179648) * 8;   dst = Wbase + 1048576 + (u - 1179648) * 8; }
    else if (u < 1179776) { src = bk + (u - 1179712) * 8;   dst = Wbase + 1049088 + (u - 1179712) * 8; }
    else if (u < 1179840) { src = bv + (u - 1179776) * 8;   dst = Wbase + 1049600 + (u - 1179776) * 8; }
    else                  { src = bo + (u - 1179840) * 8;   dst = Wbase + 1050112 + (u - 1179840) * 8; }
    *(bf16x8*)dst = cvt8(*(const float4*)src, *(const float4*)(src + 4));
}

// ---------------------------------------------------------------------------
// Pure-bf16 B^T GEMM, ROUND 10: 64x128 tile (was 128x128) for occupancy.
// Old grid 512 blocks = 2 blocks/CU = 2 waves/SIMD -- nothing hides the
// ds_read->MFMA lgkmcnt chains (why r6/r8 pipelines were neutral). New:
// grid 1024 = 4 blocks/CU scheduled (6 capacity at 24 KB LDS).
// Same verified counted-vmcnt discipline as r8: raw s_barrier + vmcnt(3)
// (3 staging loads/tile now: A is a single gl_lds). Bias prefetched first.
// 4 waves: (wave&1) = M-half (32 rows), (wave>>1) = N-half (64 cols);
// per-wave acc[2][4] 16x16 frags.
// EPI 0: out[((b*8+h)*1024+s)*64+d] bf16 (K)
// EPI 1: out[((b*8+h)*64+d)*1024+s] bf16 (V^T)
// EPI 2: out[m*512+n] f32 (final output). grid (256, 4), block 256.
// ---------------------------------------------------------------------------
template <int EPI>
__global__ __launch_bounds__(256) void gemm128(
    const u16* __restrict__ A, const u16* __restrict__ Bm,
    const u16* __restrict__ bias, void* __restrict__ out)
{
    __shared__ __align__(16) u16 AsL[2][2048];  // [64][32] unpadded (gl_lds layout)
    __shared__ __align__(16) u16 BsL[2][4096];  // [128][32]

    const int t    = threadIdx.x;
    const int wave = t >> 6, lane = t & 63;
    const int l15  = lane & 15, quad = lane >> 4;
    const int wr   = (wave & 1) * 32, wc = (wave >> 1) * 64;
    const int m0   = blockIdx.x * 64, n0 = blockIdx.y * 128;
    const int sr   = t >> 2, scol = (t & 3) * 8;

    // bias prefetch FIRST (oldest VMEM ops; retire before staging loads)
    float bvp[4];
#pragma unroll
    for (int j = 0; j < 4; j++) bvp[j] = bf2f(bias[n0 + wc + j * 16 + l15]);

    f32x4 acc[2][4];
#pragma unroll
    for (int i = 0; i < 2; i++)
#pragma unroll
        for (int j = 0; j < 4; j++) acc[i][j] = {0.f, 0.f, 0.f, 0.f};

    const u16* Ab = A  + (size_t)(m0 + sr) * 512 + scol;
    const u16* Bb = Bm + (size_t)(n0 + sr) * 512 + scol;

    // prologue: stage tiles 0 (buf0) and 1 (buf1); 6 loads outstanding
    gl_lds16(Ab,              &AsL[0][t * 8]);
    gl_lds16(Bb,              &BsL[0][t * 8]);
    gl_lds16(Bb + 32768,      &BsL[0][2048 + t * 8]);   // rows n0+64..n0+127
    gl_lds16(Ab + 32,         &AsL[1][t * 8]);
    gl_lds16(Bb + 32,         &BsL[1][t * 8]);
    gl_lds16(Bb + 32768 + 32, &BsL[1][2048 + t * 8]);

    for (int t0 = 0; t0 < 15; ++t0) {
        // wait ONLY tile t0's 3 loads (t0+1's stay in flight)
        asm volatile("s_waitcnt vmcnt(3)" ::: "memory");
        __builtin_amdgcn_s_barrier();
        __builtin_amdgcn_sched_barrier(0);
        const int c = t0 & 1;
        bf16x8 af[2], bfv[4];
#pragma unroll
        for (int i = 0; i < 2; i++) af[i]  = *(const bf16x8*)&AsL[c][(wr + i * 16 + l15) * 32 + quad * 8];
#pragma unroll
        for (int j = 0; j < 4; j++) bfv[j] = *(const bf16x8*)&BsL[c][(wc + j * 16 + l15) * 32 + quad * 8];
#pragma unroll
        for (int i = 0; i < 2; i++)
#pragma unroll
            for (int j = 0; j < 4; j++)
                acc[i][j] = __builtin_amdgcn_mfma_f32_16x16x32_bf16(af[i], bfv[j], acc[i][j], 0, 0, 0);
        __builtin_amdgcn_sched_barrier(0);
        __builtin_amdgcn_s_barrier();          // all waves done reading buf[c]
        if (t0 < 14) {                         // stage tile t0+2 into buf[c]
            const int k0n = (t0 + 2) * 32;
            gl_lds16(Ab + k0n,         &AsL[c][t * 8]);
            gl_lds16(Bb + k0n,         &BsL[c][t * 8]);
            gl_lds16(Bb + 32768 + k0n, &BsL[c][2048 + t * 8]);
        }
    }
    // tail: tile 15 (buf1), only its 3 loads outstanding
    asm volatile("s_waitcnt vmcnt(0)" ::: "memory");
    __builtin_amdgcn_s_barrier();
    __builtin_amdgcn_sched_barrier(0);
    {
        bf16x8 af[2], bfv[4];
#pragma unroll
        for (int i = 0; i < 2; i++) af[i]  = *(const bf16x8*)&AsL[1][(wr + i * 16 + l15) * 32 + quad * 8];
#pragma unroll
        for (int j = 0; j < 4; j++) bfv[j] = *(const bf16x8*)&BsL[1][(wc + j * 16 + l15) * 32 + quad * 8];
#pragma unroll
        for (int i = 0; i < 2; i++)
#pragma unroll
            for (int j = 0; j < 4; j++)
                acc[i][j] = __builtin_amdgcn_mfma_f32_16x16x32_bf16(af[i], bfv[j], acc[i][j], 0, 0, 0);
    }

#pragma unroll
    for (int j = 0; j < 4; j++) {
        const int n  = n0 + wc + j * 16 + l15;
        const float bv = bvp[j];
        const int hh = n >> 6, d = n & 63;
#pragma unroll
        for (int i = 0; i < 2; i++) {
#pragma unroll
            for (int r = 0; r < 4; r++) {
                const int m = m0 + wr + i * 16 + quad * 4 + r;
                const float val = acc[i][j][r] + bv;
                if (EPI == 0) {
                    const int b = m >> 10, s = m & 1023;
                    ((u16*)out)[((size_t)(b * 8 + hh) * 1024 + s) * 64 + d] = f2bf(val);
                } else if (EPI == 1) {
                    const int b = m >> 10, s = m & 1023;
                    ((u16*)out)[((size_t)(b * 8 + hh) * 64 + d) * 1024 + s] = f2bf(val);
                } else {
                    ((float*)out)[(size_t)m * 512 + n] = val;
                }
            }
        }
    }
}

// ---------------------------------------------------------------------------
// Flash attention, fused Q projection, mask-aware tile skipping, NO-MAX
// online softmax (scores provably bounded ~|2|; fp32 exp safe).
// Round 10 delta: Qs pitch 72 -> 64 (pad-free). Qs is read as bf16x8 exactly
// ONCE (aq); its padding bought nothing. LDS 27648 -> 26624 B -> 6 blocks/CU
// (was 5). The one-time aq read takes a 16-way conflict (~100 cyc, nil).
// Hot Ks/Vs layout unchanged. Rest: round-9 verbatim (T14 reg-staged K/V
// prefetch + non-draining barriers; counted-vmcnt phase-1 dbuf).
// K: [bh][s][d] bf16; Vt: [bh][d][s] bf16; Z: [b,s,h*64+d] bf16.
// grid (16, 128), block 256.
// ---------------------------------------------------------------------------
__global__ __launch_bounds__(256, 6) void attn(
    const u16* __restrict__ Xbf, const u16* __restrict__ Wqbf,
    const u16* __restrict__ bqbf,
    const u16* __restrict__ Kg, const u16* __restrict__ Vt,
    const int* __restrict__ xlen, u16* __restrict__ Z)
{
    // u16 map: phase1 As[2][2048]@0, Bs[2][2048]@4096 | phase2 Ks[64][72]@0,
    //          Vs[64][72]@4608 | Qs[64][64]@9216 (never overwritten).
    // total 13312 u16 = 26624 B -> 6 blocks/CU
    __shared__ __align__(16) u16 smem[13312];

    const int t    = threadIdx.x;
    const int wave = t >> 6, lane = t & 63;
    const int l15  = lane & 15, quad = lane >> 4;
    const int bh   = blockIdx.y, b = bh >> 3, h = bh & 7;
    const int bx   = blockIdx.x;
    const int xm1  = xlen[b] - 1;   // uniform -> SMEM (lgkmcnt); doesn't perturb vmcnt counts
    const int wm   = (wave & 1) * 32, wn = (wave >> 1) * 32;

    u16* Ks = smem;          // [64][72] (phase 2)
    u16* Vs = smem + 4608;   // [64][72] (phase 2)
    u16* Qs = smem + 9216;   // [64][64]

    // ---- phase 1: Q = Xbf[b, bx*64..+63, :] * Wq[h]^T + bias, times 1/8 ----
    f32x4 qa[2][2];
#pragma unroll
    for (int i = 0; i < 2; i++)
#pragma unroll
        for (int j = 0; j < 2; j++) qa[i][j] = {0.f, 0.f, 0.f, 0.f};

    const int sr = t >> 2, scol = (t & 3) * 8;
    const u16* Xb = Xbf  + (size_t)(b * 1024 + bx * 64 + sr) * 512 + scol;
    const u16* Wb = Wqbf + (size_t)(h * 64 + sr) * 512 + scol;

    // bias prefetch FIRST (oldest VMEM ops)
    float bqp[2];
#pragma unroll
    for (int j = 0; j < 2; j++) bqp[j] = bf2f(bqbf[h * 64 + wn + j * 16 + l15]);

    // prologue: k0=0 -> buf0, k0=32 -> buf1; 4 loads outstanding
    gl_lds16(Xb,      &smem[t * 8]);
    gl_lds16(Wb,      &smem[4096 + t * 8]);
    gl_lds16(Xb + 32, &smem[2048 + t * 8]);
    gl_lds16(Wb + 32, &smem[4096 + 2048 + t * 8]);

    for (int it = 0; it < 15; ++it) {
        asm volatile("s_waitcnt vmcnt(2)" ::: "memory");
        __builtin_amdgcn_s_barrier();
        __builtin_amdgcn_sched_barrier(0);
        const int c = it & 1;
        bf16x8 af[2], bfv[2];
#pragma unroll
        for (int i = 0; i < 2; i++) af[i]  = *(const bf16x8*)&smem[c * 2048 + (wm + i * 16 + l15) * 32 + quad * 8];
#pragma unroll
        for (int j = 0; j < 2; j++) bfv[j] = *(const bf16x8*)&smem[4096 + c * 2048 + (wn + j * 16 + l15) * 32 + quad * 8];
#pragma unroll
        for (int i = 0; i < 2; i++)
#pragma unroll
            for (int j = 0; j < 2; j++)
                qa[i][j] = __builtin_amdgcn_mfma_f32_16x16x32_bf16(af[i], bfv[j], qa[i][j], 0, 0, 0);
        __builtin_amdgcn_sched_barrier(0);
        __builtin_amdgcn_s_barrier();
        if (it < 14) {
            const int k0n = (it + 2) * 32;
            gl_lds16(Xb + k0n, &smem[c * 2048 + t * 8]);
            gl_lds16(Wb + k0n, &smem[4096 + c * 2048 + t * 8]);
        }
    }
    asm volatile("s_waitcnt vmcnt(0)" ::: "memory");
    __builtin_amdgcn_s_barrier();
    __builtin_amdgcn_sched_barrier(0);
    {   // it = 15, buf1
        bf16x8 af[2], bfv[2];
#pragma unroll
        for (int i = 0; i < 2; i++) af[i]  = *(const bf16x8*)&smem[2048 + (wm + i * 16 + l15) * 32 + quad * 8];
#pragma unroll
        for (int j = 0; j < 2; j++) bfv[j] = *(const bf16x8*)&smem[4096 + 2048 + (wn + j * 16 + l15) * 32 + quad * 8];
#pragma unroll
        for (int i = 0; i < 2; i++)
#pragma unroll
            for (int j = 0; j < 2; j++)
                qa[i][j] = __builtin_amdgcn_mfma_f32_16x16x32_bf16(af[i], bfv[j], qa[i][j], 0, 0, 0);
    }
    // Q (x 0.125, exact) -> unified [64][64] tile @9216 (row = q-row in block)
#pragma unroll
    for (int j = 0; j < 2; j++) {
        const int d  = wn + j * 16 + l15;
        const float bv = bqp[j];
#pragma unroll
        for (int i = 0; i < 2; i++) {
#pragma unroll
            for (int r = 0; r < 4; r++) {
                const int row = wm + i * 16 + quad * 4 + r;
                Qs[row * 64 + d] = f2bf((qa[i][j][r] + bv) * 0.125f);
            }
        }
    }
    __syncthreads();   // Q visible to all waves; Q region never written again

    bf16x8 aq[2];   // Q fragment: B-operand of swapped QK^T (col = qrow = l15)
#pragma unroll
    for (int kk = 0; kk < 2; kk++)
        aq[kk] = *(const bf16x8*)&Qs[(wave * 16 + l15) * 64 + kk * 32 + quad * 8];
    // (no barrier needed: staging below writes Ks/Vs only, disjoint from Qs)

    // ---- phase 2: 64-key tiles; skip tiles fully past xm1 (exp underflow = 0) ----
    const size_t baseKV = (size_t)bh * (S_ * DK_);
    const bool domask = (xm1 >= 1);
    const int  Slim   = domask ? xm1 : S_;   // xm1<1: uniform mask -> plain softmax
    const int  nt     = (Slim + 63) >> 6;    // # of 64-key tiles, >= 1

    f32x4 o[4];
#pragma unroll
    for (int j = 0; j < 4; j++) o[j] = {0.f, 0.f, 0.f, 0.f};
    float li = 0.f;                          // lane-local sum for q-row l15

    const int srow = t >> 3, scl = (t & 7) * 8;   // 32 rows x 64 cols per chunk
    // K-staging row permutation: srow [q2|jh1|j32] -> prow [jh1|q2|j32]
    const int prow = ((srow >> 2) & 1) * 16 + (srow >> 3) * 4 + (srow & 3);

    // global staging bases (tile offset added per iteration)
    const u16* KgR = Kg + baseKV + (size_t)srow * 64 + scl;    // +t0*64; +2048 = rows+32
    const u16* VtR = Vt + baseKV + (size_t)srow * 1024 + scl;  // +t0   ; +32768 = rows+32

    // per-tile compute (QK^T, mask, exp, pack, PV); accumulates o[], li
    auto tile_compute = [&](int t0) {
        f32x4 sc[4];
#pragma unroll
        for (int nh = 0; nh < 4; nh++) {
            f32x4 s = {0.f, 0.f, 0.f, 0.f};
#pragma unroll
            for (int kk = 0; kk < 2; kk++) {
                bf16x8 bk = *(const bf16x8*)&Ks[(nh * 16 + l15) * 72 + kk * 32 + quad * 8];
                s = __builtin_amdgcn_mfma_f32_16x16x32_bf16(bk, aq[kk], s, 0, 0, 0);
            }
            sc[nh] = s;
        }
        if (domask && (t0 + 64 > xm1)) {     // only the last partial tile masks
#pragma unroll
            for (int nh = 0; nh < 4; nh++) {
                const int kb = t0 + ((nh >> 1) << 5) + (quad << 3) + ((nh & 1) << 2);
#pragma unroll
                for (int r = 0; r < 4; r++)
                    sc[nh][r] += ((kb + r) >= xm1) ? -999999.0f : 0.0f;
            }
        }
#pragma unroll
        for (int nh = 0; nh < 4; nh++) {
#pragma unroll
            for (int r = 0; r < 4; r++) sc[nh][r] = __expf(sc[nh][r]);
            li += (sc[nh][0] + sc[nh][1]) + (sc[nh][2] + sc[nh][3]);
        }
        union { unsigned int u[4]; bf16x8 v; } ap0, ap1;
        ap0.u[0] = pk2(sc[0][0], sc[0][1]); ap0.u[1] = pk2(sc[0][2], sc[0][3]);
        ap0.u[2] = pk2(sc[1][0], sc[1][1]); ap0.u[3] = pk2(sc[1][2], sc[1][3]);
        ap1.u[0] = pk2(sc[2][0], sc[2][1]); ap1.u[1] = pk2(sc[2][2], sc[2][3]);
        ap1.u[2] = pk2(sc[3][0], sc[3][1]); ap1.u[3] = pk2(sc[3][2], sc[3][3]);
#pragma unroll
        for (int j = 0; j < 4; j++) {
            bf16x8 bv0 = *(const bf16x8*)&Vs[(j * 16 + l15) * 72 + quad * 8];
            o[j] = __builtin_amdgcn_mfma_f32_16x16x32_bf16(ap0.v, bv0, o[j], 0, 0, 0);
            bf16x8 bv1 = *(const bf16x8*)&Vs[(j * 16 + l15) * 72 + 32 + quad * 8];
            o[j] = __builtin_amdgcn_mfma_f32_16x16x32_bf16(ap1.v, bv1, o[j], 0, 0, 0);
        }
    };

    // prologue: tile 0 -> regs (4 loads in flight)
    uint4 rk0 = *(const uint4*)(KgR);
    uint4 rk1 = *(const uint4*)(KgR + 2048);
    uint4 rv0 = *(const uint4*)(VtR);
    uint4 rv1 = *(const uint4*)(VtR + 32768);

    for (int tt = 0; tt + 1 < nt; ++tt) {
        const int t0 = tt << 6;
        const int tn = t0 + 64;
        // issue next tile's loads (in flight across the barrier below)
        uint4 nk0 = *(const uint4*)(KgR + (size_t)tn * 64);
        uint4 nk1 = *(const uint4*)(KgR + (size_t)tn * 64 + 2048);
        uint4 nv0 = *(const uint4*)(VtR + tn);
        uint4 nv1 = *(const uint4*)(VtR + tn + 32768);
        // ds_write tile t (compiler inserts counted vmcnt for rk*/rv* deps)
        *(uint4*)&Ks[prow * 72 + scl]        = rk0;
        *(uint4*)&Ks[(prow + 32) * 72 + scl] = rk1;
        *(uint4*)&Vs[srow * 72 + scl]        = rv0;
        *(uint4*)&Vs[(srow + 32) * 72 + scl] = rv1;
        asm volatile("s_waitcnt lgkmcnt(0)" ::: "memory");  // writes landed
        __builtin_amdgcn_s_barrier();                        // visible to all waves
        __builtin_amdgcn_sched_barrier(0);                   // (prefetch NOT drained)
        tile_compute(t0);
        __builtin_amdgcn_sched_barrier(0);
        __builtin_amdgcn_s_barrier();   // all waves done reading Ks/Vs
        rk0 = nk0; rk1 = nk1; rv0 = nv0; rv1 = nv1;
    }
    {   // final tile (no prefetch outstanding beyond its own 4 loads)
        const int t0 = (nt - 1) << 6;
        *(uint4*)&Ks[prow * 72 + scl]        = rk0;
        *(uint4*)&Ks[(prow + 32) * 72 + scl] = rk1;
        *(uint4*)&Vs[srow * 72 + scl]        = rv0;
        *(uint4*)&Vs[(srow + 32) * 72 + scl] = rv1;
        asm volatile("s_waitcnt lgkmcnt(0)" ::: "memory");
        __builtin_amdgcn_s_barrier();
        __builtin_amdgcn_sched_barrier(0);
        tile_compute(t0);
    }

    // rowsum for q-row l15 lives across the 4 quads -> butterfly, invert,
    // then redistribute to the o-rows (row = quad*4+r lives at lane quad*4+r)
    float rs = li;
    rs += __shfl_xor(rs, 16);
    rs += __shfl_xor(rs, 32);
    const float linv = 1.0f / rs;
    float lr[4];
#pragma unroll
    for (int r = 0; r < 4; r++) lr[r] = __shfl(linv, quad * 4 + r);

#pragma unroll
    for (int j = 0; j < 4; j++) {
#pragma unroll
        for (int r = 0; r < 4; r++) {
            const int s = bx * 64 + wave * 16 + quad * 4 + r;
            Z[((size_t)(b * 1024 + s)) * 512 + h * 64 + j * 16 + l15] = f2bf(o[j][r] * lr[r]);
        }
    }
}

// ---------------------------------------------------------------------------
extern "C" void kernel_launch(void* const* d_in, const int* in_sizes, int n_in,
                              void* d_out, int out_size, void* d_ws, size_t ws_size,
                              hipStream_t stream)
{
    (void)in_sizes; (void)n_in; (void)out_size; (void)ws_size;

    const float* x    = (const float*)d_in[0];
    const int*   xlen = (const int*)d_in[1];
    const float* WQw  = (const float*)d_in[2];
    const float* WQb  = (const float*)d_in[3];
    const float* WKw  = (const float*)d_in[4];
    const float* WKb  = (const float*)d_in[5];
    const float* WVw  = (const float*)d_in[6];
    const float* WVb  = (const float*)d_in[7];
    const float* WOw  = (const float*)d_in[8];
    const float* WOb  = (const float*)d_in[9];

    const size_t NQ = (size_t)B_ * H_ * S_ * DK_;  // 8388608
    // ws: Kb | Zb | bf16 weights+biases  (~35.7 MB)
    u16* Kb    = (u16*)d_ws;
    u16* Zb    = Kb + NQ;
    u16* Wbase = Zb + NQ;
    u16* WQbf  = Wbase;
    u16* WKbf  = Wbase + 262144;
    u16* WVbf  = Wbase + 524288;
    u16* WObf  = Wbase + 786432;
    u16* bqbf  = Wbase + 1048576;
    u16* bkbf  = Wbase + 1049088;
    u16* bvbf  = Wbase + 1049600;
    u16* bobf  = Wbase + 1050112;
    // d_out (33.55 MB f32) temporarily holds: Xbf @0, V^T @NQ (both dead
    // before the final GEMM overwrites d_out)
    u16* Xbf = (u16*)d_out;
    u16* Vb  = Xbf + NQ;

    dim3 blk(256);
    cvt_all<<<dim3(4609), blk, 0, stream>>>(x, WQw, WKw, WVw, WOw,
                                            WQb, WKb, WVb, WOb, Xbf, Wbase);

    dim3 gGemm(256, 4);
    gemm128<0><<<gGemm, blk, 0, stream>>>(Xbf, WKbf, bkbf, Kb);   // K proj
    gemm128<1><<<gGemm, blk, 0, stream>>>(Xbf, WVbf, bvbf, Vb);   // V^T proj

    dim3 gAttn(16, 128);
    attn<<<gAttn, blk, 0, stream>>>(Xbf, WQbf, bqbf, Kb, Vb, xlen, Zb);

    gemm128<2><<<gGemm, blk, 0, stream>>>(Zb, WObf, bobf, d_out); // out proj (f32)
}

// Round 11
// 194.888 us; speedup vs baseline: 1.0446x; 1.0446x over previous
//
#include <hip/hip_runtime.h>
#include <hip/hip_bf16.h>

typedef short bf16x8 __attribute__((ext_vector_type(8)));
typedef float f32x4 __attribute__((ext_vector_type(4)));
typedef unsigned short u16;

#define B_   16
#define S_   1024
#define F_   512
#define H_   8
#define DK_  64

// Inputs/outputs are FLOAT32 (established rounds 3/7). cvt_all converts x +
// weights to bf16 once; all hot loops are pure bf16. Intermediates bf16.

__device__ __forceinline__ u16 f2bf(float f) {
    union { float f; unsigned int u; } v; v.f = f;
    return (u16)((v.u + 0x7FFFu + ((v.u >> 16) & 1u)) >> 16);
}
__device__ __forceinline__ float bf2f(u16 h) {
    union { unsigned int u; float f; } v; v.u = ((unsigned int)h) << 16;
    return v.f;
}
__device__ __forceinline__ bf16x8 cvt8(float4 a, float4 b) {
    union { u16 u[8]; bf16x8 v; } r;
    r.u[0] = f2bf(a.x); r.u[1] = f2bf(a.y); r.u[2] = f2bf(a.z); r.u[3] = f2bf(a.w);
    r.u[4] = f2bf(b.x); r.u[5] = f2bf(b.y); r.u[6] = f2bf(b.z); r.u[7] = f2bf(b.w);
    return r.v;
}
// pair-pack f32->bf16 (compiler emits v_cvt_pk_bf16_f32; RNE, matches f2bf)
__device__ __forceinline__ unsigned int pk2(float lo, float hi) {
    union { __hip_bfloat162 h; unsigned int u; } c;
    c.h = __float22bfloat162_rn(make_float2(lo, hi));
    return c.u;
}

// async global->LDS, 16 B per lane. LDS dest = wave-uniform base + lane*16.
__device__ __forceinline__ void gl_lds16(const u16* g, u16* l) {
    __builtin_amdgcn_global_load_lds(
        (const __attribute__((address_space(1))) unsigned int*)g,
        (__attribute__((address_space(3))) unsigned int*)l,
        16, 0, 0);
}

// ---------------------------------------------------------------------------
// One-shot f32 -> bf16 conversion of x and all weights/biases.
// unit = 8 elems. Segments (units): x 1048576 | WQ/WK/WV/WO 32768 each |
// bq/bk/bv/bo 64 each. grid 4609 x 256 (exact).
// ---------------------------------------------------------------------------
__global__ __launch_bounds__(256) void cvt_all(
    const float* __restrict__ x,
    const float* __restrict__ wq, const float* __restrict__ wk,
    const float* __restrict__ wv, const float* __restrict__ wo,
    const float* __restrict__ bq, const float* __restrict__ bk,
    const float* __restrict__ bv, const float* __restrict__ bo,
    u16* __restrict__ Xbf, u16* __restrict__ Wbase)
{
    const size_t u = (size_t)blockIdx.x * 256 + threadIdx.x;
    const float* src; u16* dst;
    if (u < 1048576)      { src = x  + u * 8;               dst = Xbf + u * 8; }
    else if (u < 1081344) { src = wq + (u - 1048576) * 8;   dst = Wbase + (u - 1048576) * 8; }
    else if (u < 1114112) { src = wk + (u - 1081344) * 8;   dst = Wbase +  262144 + (u - 1081344) * 8; }
    else if (u < 1146880) { src = wv + (u - 1114112) * 8;   dst = Wbase +  524288 + (u - 1114112) * 8; }
    else if (u < 1179648) { src = wo + (u - 1146880) * 8;   dst = Wbase +  786432 + (u - 1146880) * 8; }
    else if (u < 1179712) { src = bq + (u - 1179648) * 8;   dst = Wbase + 1048576 + (u - 1179648) * 8; }
    else if (u < 1179776) { src = bk + (u - 1179712) * 8;   dst = Wbase + 1049088 + (u - 1179712) * 8; }
    else if (u < 1179840) { src = bv + (u - 1179776) * 8;   dst = Wbase + 1049600 + (u - 1179776) * 8; }
    else                  { src = bo + (u - 1179840) * 8;   dst = Wbase + 1050112 + (u - 1179840) * 8; }
    *(bf16x8*)dst = cvt8(*(const float4*)src, *(const float4*)(src + 4));
}

// ---------------------------------------------------------------------------
// m97-style pure-bf16 B^T GEMM (round-8/9 version, verified best): 128x128
// tile, 2-phase dbuf + COUNTED vmcnt (raw s_barrier; vmcnt(4) keeps next
// tile's loads in flight). Bias prefetched before staging. (Round-10's
// 64x128 retile regressed: B panels refetched by 2x the blocks.)
// EPI 0: out[((b*8+h)*1024+s)*64+d] bf16 (K)
// EPI 1: out[((b*8+h)*64+d)*1024+s] bf16 (V^T)
// EPI 2: out[m*512+n] f32 (final output). grid (128, 4), block 256.
// ---------------------------------------------------------------------------
template <int EPI>
__global__ __launch_bounds__(256) void gemm128(
    const u16* __restrict__ A, const u16* __restrict__ Bm,
    const u16* __restrict__ bias, void* __restrict__ out)
{
    __shared__ __align__(16) u16 AsL[2][4096];  // [128][32] unpadded (gl_lds layout)
    __shared__ __align__(16) u16 BsL[2][4096];

    const int t    = threadIdx.x;
    const int wave = t >> 6, lane = t & 63;
    const int l15  = lane & 15, quad = lane >> 4;
    const int wr   = (wave & 1) * 64, wc = (wave >> 1) * 64;
    const int m0   = blockIdx.x * 128, n0 = blockIdx.y * 128;
    const int sr   = t >> 2, scol = (t & 3) * 8;

    // bias prefetch FIRST (oldest VMEM ops; retire before staging loads)
    float bvp[4];
#pragma unroll
    for (int j = 0; j < 4; j++) bvp[j] = bf2f(bias[n0 + wc + j * 16 + l15]);

    f32x4 acc[4][4];
#pragma unroll
    for (int i = 0; i < 4; i++)
#pragma unroll
        for (int j = 0; j < 4; j++) acc[i][j] = {0.f, 0.f, 0.f, 0.f};

    const u16* Ab = A  + (size_t)(m0 + sr) * 512 + scol;
    const u16* Bb = Bm + (size_t)(n0 + sr) * 512 + scol;

    // prologue: stage tiles 0 (buf0) and 1 (buf1); 8 loads outstanding
    gl_lds16(Ab,              &AsL[0][t * 8]);
    gl_lds16(Ab + 32768,      &AsL[0][2048 + t * 8]);
    gl_lds16(Bb,              &BsL[0][t * 8]);
    gl_lds16(Bb + 32768,      &BsL[0][2048 + t * 8]);
    gl_lds16(Ab + 32,         &AsL[1][t * 8]);
    gl_lds16(Ab + 32768 + 32, &AsL[1][2048 + t * 8]);
    gl_lds16(Bb + 32,         &BsL[1][t * 8]);
    gl_lds16(Bb + 32768 + 32, &BsL[1][2048 + t * 8]);

    for (int t0 = 0; t0 < 15; ++t0) {
        // wait ONLY tile t0's 4 loads (t0+1's stay in flight)
        asm volatile("s_waitcnt vmcnt(4)" ::: "memory");
        __builtin_amdgcn_s_barrier();
        __builtin_amdgcn_sched_barrier(0);
        const int c = t0 & 1;
        bf16x8 af[4], bfv[4];
#pragma unroll
        for (int i = 0; i < 4; i++) af[i]  = *(const bf16x8*)&AsL[c][(wr + i * 16 + l15) * 32 + quad * 8];
#pragma unroll
        for (int j = 0; j < 4; j++) bfv[j] = *(const bf16x8*)&BsL[c][(wc + j * 16 + l15) * 32 + quad * 8];
#pragma unroll
        for (int i = 0; i < 4; i++)
#pragma unroll
            for (int j = 0; j < 4; j++)
                acc[i][j] = __builtin_amdgcn_mfma_f32_16x16x32_bf16(af[i], bfv[j], acc[i][j], 0, 0, 0);
        __builtin_amdgcn_sched_barrier(0);
        __builtin_amdgcn_s_barrier();          // all waves done reading buf[c]
        if (t0 < 14) {                         // stage tile t0+2 into buf[c]
            const int k0n = (t0 + 2) * 32;
            gl_lds16(Ab + k0n,         &AsL[c][t * 8]);
            gl_lds16(Ab + 32768 + k0n, &AsL[c][2048 + t * 8]);
            gl_lds16(Bb + k0n,         &BsL[c][t * 8]);
            gl_lds16(Bb + 32768 + k0n, &BsL[c][2048 + t * 8]);
        }
    }
    // tail: tile 15 (buf1), only its 4 loads outstanding
    asm volatile("s_waitcnt vmcnt(0)" ::: "memory");
    __builtin_amdgcn_s_barrier();
    __builtin_amdgcn_sched_barrier(0);
    {
        bf16x8 af[4], bfv[4];
#pragma unroll
        for (int i = 0; i < 4; i++) af[i]  = *(const bf16x8*)&AsL[1][(wr + i * 16 + l15) * 32 + quad * 8];
#pragma unroll
        for (int j = 0; j < 4; j++) bfv[j] = *(const bf16x8*)&BsL[1][(wc + j * 16 + l15) * 32 + quad * 8];
#pragma unroll
        for (int i = 0; i < 4; i++)
#pragma unroll
            for (int j = 0; j < 4; j++)
                acc[i][j] = __builtin_amdgcn_mfma_f32_16x16x32_bf16(af[i], bfv[j], acc[i][j], 0, 0, 0);
    }

#pragma unroll
    for (int j = 0; j < 4; j++) {
        const int n  = n0 + wc + j * 16 + l15;
        const float bv = bvp[j];
        const int hh = n >> 6, d = n & 63;
#pragma unroll
        for (int i = 0; i < 4; i++) {
#pragma unroll
            for (int r = 0; r < 4; r++) {
                const int m = m0 + wr + i * 16 + quad * 4 + r;
                const float val = acc[i][j][r] + bv;
                if (EPI == 0) {
                    const int b = m >> 10, s = m & 1023;
                    ((u16*)out)[((size_t)(b * 8 + hh) * 1024 + s) * 64 + d] = f2bf(val);
                } else if (EPI == 1) {
                    const int b = m >> 10, s = m & 1023;
                    ((u16*)out)[((size_t)(b * 8 + hh) * 64 + d) * 1024 + s] = f2bf(val);
                } else {
                    ((float*)out)[(size_t)m * 512 + n] = val;
                }
            }
        }
    }
}

// ---------------------------------------------------------------------------
// Flash attention, fused Q projection, mask-aware tile skipping, NO-MAX
// online softmax (scores provably bounded ~|2|; fp32 exp safe).
// Round 11 delta (attn ONLY, vs round 9): T2 XOR-swizzled pad-free Ks/Vs
// [64][64], u16 idx ^= 8*(row&7) on BOTH ds_write and ds_read (involution;
// possible because r9 moved staging to registers -- gl_lds had blocked it).
// Bank math: old pitch-72 reads were ~8-way conflicted (row stride 36 dw
// = 4 mod 32 -> quarter-phase lanes pile into one 4-bank group); swizzled
// reads/writes are <=2-way (free). Targets the measured 7.1M conflicts.
// smem DECLARED 13824 u16 = 27648 B to pin 5 blocks/CU (round 10 measured
// 6 blocks/CU = L2 thrash: FETCH +11%, WRITE +112%, dur +7%).
// Rest: round-9 verbatim (T14 reg-staged K/V prefetch + non-draining
// barriers; counted-vmcnt phase-1 dbuf; round-8 epilogue).
// K: [bh][s][d] bf16; Vt: [bh][d][s] bf16; Z: [b,s,h*64+d] bf16.
// grid (16, 128), block 256.
// ---------------------------------------------------------------------------
__global__ __launch_bounds__(256, 5) void attn(
    const u16* __restrict__ Xbf, const u16* __restrict__ Wqbf,
    const u16* __restrict__ bqbf,
    const u16* __restrict__ Kg, const u16* __restrict__ Vt,
    const int* __restrict__ xlen, u16* __restrict__ Z)
{
    // u16 map: phase1 As[2][2048]@0, Bs[2][2048]@4096 (ends 8192) |
    // phase2 Ks[64][64]@0 (swz), Vs[64][64]@4096 (swz) | Qs[64][72]@8192.
    // used 12800 u16; DECLARED 13824 u16 = 27648 B -> 5 blocks/CU (pinned).
    __shared__ __align__(16) u16 smem[13824];

    const int t    = threadIdx.x;
    const int wave = t >> 6, lane = t & 63;
    const int l15  = lane & 15, quad = lane >> 4;
    const int bh   = blockIdx.y, b = bh >> 3, h = bh & 7;
    const int bx   = blockIdx.x;
    const int xm1  = xlen[b] - 1;   // uniform -> SMEM (lgkmcnt); doesn't perturb vmcnt counts
    const int wm   = (wave & 1) * 32, wn = (wave >> 1) * 32;

    u16* Ks = smem;          // [64][64] swizzled (phase 2)
    u16* Vs = smem + 4096;   // [64][64] swizzled (phase 2)
    u16* Qs = smem + 8192;   // [64][72]

    // ---- phase 1: Q = Xbf[b, bx*64..+63, :] * Wq[h]^T + bias, times 1/8 ----
    f32x4 qa[2][2];
#pragma unroll
    for (int i = 0; i < 2; i++)
#pragma unroll
        for (int j = 0; j < 2; j++) qa[i][j] = {0.f, 0.f, 0.f, 0.f};

    const int sr = t >> 2, scol = (t & 3) * 8;
    const u16* Xb = Xbf  + (size_t)(b * 1024 + bx * 64 + sr) * 512 + scol;
    const u16* Wb = Wqbf + (size_t)(h * 64 + sr) * 512 + scol;

    // bias prefetch FIRST (oldest VMEM ops)
    float bqp[2];
#pragma unroll
    for (int j = 0; j < 2; j++) bqp[j] = bf2f(bqbf[h * 64 + wn + j * 16 + l15]);

    // prologue: k0=0 -> buf0, k0=32 -> buf1; 4 loads outstanding
    gl_lds16(Xb,      &smem[t * 8]);
    gl_lds16(Wb,      &smem[4096 + t * 8]);
    gl_lds16(Xb + 32, &smem[2048 + t * 8]);
    gl_lds16(Wb + 32, &smem[4096 + 2048 + t * 8]);

    for (int it = 0; it < 15; ++it) {
        asm volatile("s_waitcnt vmcnt(2)" ::: "memory");
        __builtin_amdgcn_s_barrier();
        __builtin_amdgcn_sched_barrier(0);
        const int c = it & 1;
        bf16x8 af[2], bfv[2];
#pragma unroll
        for (int i = 0; i < 2; i++) af[i]  = *(const bf16x8*)&smem[c * 2048 + (wm + i * 16 + l15) * 32 + quad * 8];
#pragma unroll
        for (int j = 0; j < 2; j++) bfv[j] = *(const bf16x8*)&smem[4096 + c * 2048 + (wn + j * 16 + l15) * 32 + quad * 8];
#pragma unroll
        for (int i = 0; i < 2; i++)
#pragma unroll
            for (int j = 0; j < 2; j++)
                qa[i][j] = __builtin_amdgcn_mfma_f32_16x16x32_bf16(af[i], bfv[j], qa[i][j], 0, 0, 0);
        __builtin_amdgcn_sched_barrier(0);
        __builtin_amdgcn_s_barrier();
        if (it < 14) {
            const int k0n = (it + 2) * 32;
            gl_lds16(Xb + k0n, &smem[c * 2048 + t * 8]);
            gl_lds16(Wb + k0n, &smem[4096 + c * 2048 + t * 8]);
        }
    }
    asm volatile("s_waitcnt vmcnt(0)" ::: "memory");
    __builtin_amdgcn_s_barrier();
    __builtin_amdgcn_sched_barrier(0);
    {   // it = 15, buf1
        bf16x8 af[2], bfv[2];
#pragma unroll
        for (int i = 0; i < 2; i++) af[i]  = *(const bf16x8*)&smem[2048 + (wm + i * 16 + l15) * 32 + quad * 8];
#pragma unroll
        for (int j = 0; j < 2; j++) bfv[j] = *(const bf16x8*)&smem[4096 + 2048 + (wn + j * 16 + l15) * 32 + quad * 8];
#pragma unroll
        for (int i = 0; i < 2; i++)
#pragma unroll
            for (int j = 0; j < 2; j++)
                qa[i][j] = __builtin_amdgcn_mfma_f32_16x16x32_bf16(af[i], bfv[j], qa[i][j], 0, 0, 0);
    }
    // Q (x 0.125, exact) -> unified [64][72] tile @8192 (row = q-row in block)
#pragma unroll
    for (int j = 0; j < 2; j++) {
        const int d  = wn + j * 16 + l15;
        const float bv = bqp[j];
#pragma unroll
        for (int i = 0; i < 2; i++) {
#pragma unroll
            for (int r = 0; r < 4; r++) {
                const int row = wm + i * 16 + quad * 4 + r;
                Qs[row * 72 + d] = f2bf((qa[i][j][r] + bv) * 0.125f);
            }
        }
    }
    __syncthreads();   // Q visible to all waves; Q region never written again

    bf16x8 aq[2];   // Q fragment: B-operand of swapped QK^T (col = qrow = l15)
#pragma unroll
    for (int kk = 0; kk < 2; kk++)
        aq[kk] = *(const bf16x8*)&Qs[(wave * 16 + l15) * 72 + kk * 32 + quad * 8];
    // (no barrier needed: staging below writes Ks/Vs only, disjoint from Qs)

    // ---- phase 2: 64-key tiles; skip tiles fully past xm1 (exp underflow = 0) ----
    const size_t baseKV = (size_t)bh * (S_ * DK_);
    const bool domask = (xm1 >= 1);
    const int  Slim   = domask ? xm1 : S_;   // xm1<1: uniform mask -> plain softmax
    const int  nt     = (Slim + 63) >> 6;    // # of 64-key tiles, >= 1

    f32x4 o[4];
#pragma unroll
    for (int j = 0; j < 4; j++) o[j] = {0.f, 0.f, 0.f, 0.f};
    float li = 0.f;                          // lane-local sum for q-row l15

    const int srow = t >> 3, scl = (t & 7) * 8;   // 32 rows x 64 cols per chunk
    // K-staging row permutation: srow [q2|jh1|j32] -> prow [jh1|q2|j32]
    const int prow = ((srow >> 2) & 1) * 16 + (srow >> 3) * 4 + (srow & 3);
    // T2 swizzle constants: u16 idx ^= 8*(row&7). (row+32)&7 == row&7.
    const int swK = 8 * (prow & 7);
    const int swV = 8 * (srow & 7);
    const int swR = 8 * (l15 & 7);    // read side: row&7 = l15&7 for row=nh*16+l15

    // global staging bases (tile offset added per iteration)
    const u16* KgR = Kg + baseKV + (size_t)srow * 64 + scl;    // +t0*64; +2048 = rows+32
    const u16* VtR = Vt + baseKV + (size_t)srow * 1024 + scl;  // +t0   ; +32768 = rows+32

    // per-tile compute (QK^T, mask, exp, pack, PV); accumulates o[], li
    auto tile_compute = [&](int t0) {
        f32x4 sc[4];
#pragma unroll
        for (int nh = 0; nh < 4; nh++) {
            f32x4 s = {0.f, 0.f, 0.f, 0.f};
#pragma unroll
            for (int kk = 0; kk < 2; kk++) {
                bf16x8 bk = *(const bf16x8*)&Ks[(((nh * 16 + l15) * 64) + kk * 32 + quad * 8) ^ swR];
                s = __builtin_amdgcn_mfma_f32_16x16x32_bf16(bk, aq[kk], s, 0, 0, 0);
            }
            sc[nh] = s;
        }
        if (domask && (t0 + 64 > xm1)) {     // only the last partial tile masks
#pragma unroll
            for (int nh = 0; nh < 4; nh++) {
                const int kb = t0 + ((nh >> 1) << 5) + (quad << 3) + ((nh & 1) << 2);
#pragma unroll
                for (int r = 0; r < 4; r++)
                    sc[nh][r] += ((kb + r) >= xm1) ? -999999.0f : 0.0f;
            }
        }
#pragma unroll
        for (int nh = 0; nh < 4; nh++) {
#pragma unroll
            for (int r = 0; r < 4; r++) sc[nh][r] = __expf(sc[nh][r]);
            li += (sc[nh][0] + sc[nh][1]) + (sc[nh][2] + sc[nh][3]);
        }
        union { unsigned int u[4]; bf16x8 v; } ap0, ap1;
        ap0.u[0] = pk2(sc[0][0], sc[0][1]); ap0.u[1] = pk2(sc[0][2], sc[0][3]);
        ap0.u[2] = pk2(sc[1][0], sc[1][1]); ap0.u[3] = pk2(sc[1][2], sc[1][3]);
        ap1.u[0] = pk2(sc[2][0], sc[2][1]); ap1.u[1] = pk2(sc[2][2], sc[2][3]);
        ap1.u[2] = pk2(sc[3][0], sc[3][1]); ap1.u[3] = pk2(sc[3][2], sc[3][3]);
#pragma unroll
        for (int j = 0; j < 4; j++) {
            bf16x8 bv0 = *(const bf16x8*)&Vs[(((j * 16 + l15) * 64) + quad * 8) ^ swR];
            o[j] = __builtin_amdgcn_mfma_f32_16x16x32_bf16(ap0.v, bv0, o[j], 0, 0, 0);
            bf16x8 bv1 = *(const bf16x8*)&Vs[(((j * 16 + l15) * 64) + 32 + quad * 8) ^ swR];
            o[j] = __builtin_amdgcn_mfma_f32_16x16x32_bf16(ap1.v, bv1, o[j], 0, 0, 0);
        }
    };

    // prologue: tile 0 -> regs (4 loads in flight)
    uint4 rk0 = *(const uint4*)(KgR);
    uint4 rk1 = *(const uint4*)(KgR + 2048);
    uint4 rv0 = *(const uint4*)(VtR);
    uint4 rv1 = *(const uint4*)(VtR + 32768);

    for (int tt = 0; tt + 1 < nt; ++tt) {
        const int t0 = tt << 6;
        const int tn = t0 + 64;
        // issue next tile's loads (in flight across the barrier below)
        uint4 nk0 = *(const uint4*)(KgR + (size_t)tn * 64);
        uint4 nk1 = *(const uint4*)(KgR + (size_t)tn * 64 + 2048);
        uint4 nv0 = *(const uint4*)(VtR + tn);
        uint4 nv1 = *(const uint4*)(VtR + tn + 32768);
        // ds_write tile t, swizzled (compiler inserts counted vmcnt for deps)
        *(uint4*)&Ks[(prow * 64 + scl) ^ swK]        = rk0;
        *(uint4*)&Ks[((prow + 32) * 64 + scl) ^ swK] = rk1;
        *(uint4*)&Vs[(srow * 64 + scl) ^ swV]        = rv0;
        *(uint4*)&Vs[((srow + 32) * 64 + scl) ^ swV] = rv1;
        asm volatile("s_waitcnt lgkmcnt(0)" ::: "memory");  // writes landed
        __builtin_amdgcn_s_barrier();                        // visible to all waves
        __builtin_amdgcn_sched_barrier(0);                   // (prefetch NOT drained)
        tile_compute(t0);
        __builtin_amdgcn_sched_barrier(0);
        __builtin_amdgcn_s_barrier();   // all waves done reading Ks/Vs
        rk0 = nk0; rk1 = nk1; rv0 = nv0; rv1 = nv1;
    }
    {   // final tile (no prefetch outstanding beyond its own 4 loads)
        const int t0 = (nt - 1) << 6;
        *(uint4*)&Ks[(prow * 64 + scl) ^ swK]        = rk0;
        *(uint4*)&Ks[((prow + 32) * 64 + scl) ^ swK] = rk1;
        *(uint4*)&Vs[(srow * 64 + scl) ^ swV]        = rv0;
        *(uint4*)&Vs[((srow + 32) * 64 + scl) ^ swV] = rv1;
        asm volatile("s_waitcnt lgkmcnt(0)" ::: "memory");
        __builtin_amdgcn_s_barrier();
        __builtin_amdgcn_sched_barrier(0);
        tile_compute(t0);
    }

    // rowsum for q-row l15 lives across the 4 quads -> butterfly, invert,
    // then redistribute to the o-rows (row = quad*4+r lives at lane quad*4+r)
    float rs = li;
    rs += __shfl_xor(rs, 16);
    rs += __shfl_xor(rs, 32);
    const float linv = 1.0f / rs;
    float lr[4];
#pragma unroll
    for (int r = 0; r < 4; r++) lr[r] = __shfl(linv, quad * 4 + r);

#pragma unroll
    for (int j = 0; j < 4; j++) {
#pragma unroll
        for (int r = 0; r < 4; r++) {
            const int s = bx * 64 + wave * 16 + quad * 4 + r;
            Z[((size_t)(b * 1024 + s)) * 512 + h * 64 + j * 16 + l15] = f2bf(o[j][r] * lr[r]);
        }
    }
}

// ---------------------------------------------------------------------------
extern "C" void kernel_launch(void* const* d_in, const int* in_sizes, int n_in,
                              void* d_out, int out_size, void* d_ws, size_t ws_size,
                              hipStream_t stream)
{
    (void)in_sizes; (void)n_in; (void)out_size; (void)ws_size;

    const float* x    = (const float*)d_in[0];
    const int*   xlen = (const int*)d_in[1];
    const float* WQw  = (const float*)d_in[2];
    const float* WQb  = (const float*)d_in[3];
    const float* WKw  = (const float*)d_in[4];
    const float* WKb  = (const float*)d_in[5];
    const float* WVw  = (const float*)d_in[6];
    const float* WVb  = (const float*)d_in[7];
    const float* WOw  = (const float*)d_in[8];
    const float* WOb  = (const float*)d_in[9];

    const size_t NQ = (size_t)B_ * H_ * S_ * DK_;  // 8388608
    // ws: Kb | Zb | bf16 weights+biases  (~35.7 MB)
    u16* Kb    = (u16*)d_ws;
    u16* Zb    = Kb + NQ;
    u16* Wbase = Zb + NQ;
    u16* WQbf  = Wbase;
    u16* WKbf  = Wbase + 262144;
    u16* WVbf  = Wbase + 524288;
    u16* WObf  = Wbase + 786432;
    u16* bqbf  = Wbase + 1048576;
    u16* bkbf  = Wbase + 1049088;
    u16* bvbf  = Wbase + 1049600;
    u16* bobf  = Wbase + 1050112;
    // d_out (33.55 MB f32) temporarily holds: Xbf @0, V^T @NQ (both dead
    // before the final GEMM overwrites d_out)
    u16* Xbf = (u16*)d_out;
    u16* Vb  = Xbf + NQ;

    dim3 blk(256);
    cvt_all<<<dim3(4609), blk, 0, stream>>>(x, WQw, WKw, WVw, WOw,
                                            WQb, WKb, WVb, WOb, Xbf, Wbase);

    dim3 gGemm(128, 4);
    gemm128<0><<<gGemm, blk, 0, stream>>>(Xbf, WKbf, bkbf, Kb);   // K proj
    gemm128<1><<<gGemm, blk, 0, stream>>>(Xbf, WVbf, bvbf, Vb);   // V^T proj

    dim3 gAttn(16, 128);
    attn<<<gAttn, blk, 0, stream>>>(Xbf, WQbf, bqbf, Kb, Vb, xlen, Zb);

    gemm128<2><<<gGemm, blk, 0, stream>>>(Zb, WObf, bobf, d_out); // out proj (f32)
}